// Round 8
// baseline (232.713 us; speedup 1.0000x reference)
//
#include <hip/hip_runtime.h>

// LIF scan, T=8, N=4M fp32. 256 MiB logical traffic, ideal ~40-43 us at the
// 6.3-6.7 TB/s this device demonstrably sustains (copy m13, harness fills).
// History: R1-R4 capped at 2.2 TB/s by the cache-allocate read path -> fixed
// by NT LOADS (R5, kernel ~79 us). R5==R6: forced per-wave MLP adds nothing.
// R7 (all-asm partial-drain pipeline) broke correctness -> asm reverted.
// R8 single-variable: keep nt loads, use PLAIN stores. Both 6.3+ TB/s
// writers in this trace (fill, copy) use plain stores; nt stores may bypass
// L2 write-combining and cap the store path. Never tested with nt loads.

#define LIF_THRESH 0.5f
#define LIF_BETA   0.25f
#define LIF_T      8

typedef float v4f __attribute__((ext_vector_type(4)));

__global__ __launch_bounds__(256) void lif_kernel(const v4f* __restrict__ x,
                                                  v4f* __restrict__ out,
                                                  int n4) {
    int i = blockIdx.x * 256 + threadIdx.x;
    if (i >= n4) return;

    // Streaming loads: read-once data, nt policy skips cache allocate (the
    // R5 discovery that broke the 2.2 TB/s plateau).
    v4f xv[LIF_T];
#pragma unroll
    for (int t = 0; t < LIF_T; ++t) {
        xv[t] = __builtin_nontemporal_load(&x[(size_t)t * n4 + i]);
    }

    float m0 = 0.f, m1 = 0.f, m2 = 0.f, m3 = 0.f;
#pragma unroll
    for (int t = 0; t < LIF_T; ++t) {
        v4f xt = xv[t];
        m0 = m0 * LIF_BETA + xt.x;
        m1 = m1 * LIF_BETA + xt.y;
        m2 = m2 * LIF_BETA + xt.z;
        m3 = m3 * LIF_BETA + xt.w;

        v4f s;
        s.x = (m0 >= LIF_THRESH) ? 1.f : 0.f;
        s.y = (m1 >= LIF_THRESH) ? 1.f : 0.f;
        s.z = (m2 >= LIF_THRESH) ? 1.f : 0.f;
        s.w = (m3 >= LIF_THRESH) ? 1.f : 0.f;

        m0 = (m0 >= LIF_THRESH) ? 0.f : m0;
        m1 = (m1 >= LIF_THRESH) ? 0.f : m1;
        m2 = (m2 >= LIF_THRESH) ? 0.f : m2;
        m3 = (m3 >= LIF_THRESH) ? 0.f : m3;

        // PLAIN store: write-back through L2 write-combining, like the
        // 6.3-6.7 TB/s fill/copy paths. (The single variable vs R5.)
        out[(size_t)t * n4 + i] = s;
    }
}

extern "C" void kernel_launch(void* const* d_in, const int* in_sizes, int n_in,
                              void* d_out, int out_size, void* d_ws, size_t ws_size,
                              hipStream_t stream) {
    const v4f* x = (const v4f*)d_in[0];
    v4f* out = (v4f*)d_out;

    long long total = in_sizes[0];
    int n = (int)(total / LIF_T);   // 4,194,304 floats per timestep
    int n4 = n / 4;                 // 1,048,576 float4 per timestep

    dim3 block(256);
    dim3 grid((n4 + 255) / 256);    // 4096 blocks
    lif_kernel<<<grid, block, 0, stream>>>(x, out, n4);
}

// Round 9
// 224.898 us; speedup vs baseline: 1.0348x; 1.0348x over previous
//
#include <hip/hip_runtime.h>

// LIF scan, T=8, N=4M fp32. 256 MiB logical; device sustains 6.3-6.7 TB/s on
// 1-2-stream patterns (copy/fill) in this very trace -> ~43 us ideal.
// Ladder: R1-R4 capped 2.2 TB/s by cache-allocate read path -> NT LOADS fixed
// it (R5, ~78 us, ~3.4 TB/s). R5==R6==R8: burst depth, pipeline shape, store
// policy all neutral. Residual theory: per-CU translation working set (16
// concurrent 16MiB-strided streams/wave x ~16 resident blocks ~ 256 pages)
// thrashes UTCL1; copy/fill touch a handful. R9: 512 blocks x 8 contiguous
// chunks -> 32 pages/CU stable; depth-2 C prefetch guards MLP at 8 waves/CU.

#define LIF_THRESH 0.5f
#define LIF_BETA   0.25f
#define LIF_T      8
#define BLOCK      256
#define JITER      8

typedef float v4f __attribute__((ext_vector_type(4)));

__global__ __launch_bounds__(BLOCK) void lif_kernel(const v4f* __restrict__ x,
                                                    v4f* __restrict__ out,
                                                    int n4) {
    // Block b owns contiguous columns [b*BLOCK*JITER, (b+1)*BLOCK*JITER).
    const int base = blockIdx.x * (BLOCK * JITER) + threadIdx.x;

    v4f cur[LIF_T], nxt[LIF_T];

    // Prologue: chunk 0 loads (nt: read-once streaming, the R5 win).
#pragma unroll
    for (int t = 0; t < LIF_T; ++t)
        cur[t] = __builtin_nontemporal_load(&x[(size_t)t * n4 + base]);

#pragma unroll
    for (int j = 0; j < JITER; ++j) {
        const int c = base + j * BLOCK;

        // Prefetch chunk j+1 BEFORE consuming chunk j: independent loads the
        // compiler can hoist above the compute/stores below -> >=8 outstanding
        // per wave even at 8 waves/CU.
        if (j + 1 < JITER) {
            const int cn = c + BLOCK;
#pragma unroll
            for (int t = 0; t < LIF_T; ++t)
                nxt[t] = __builtin_nontemporal_load(&x[(size_t)t * n4 + cn]);
        }

        float m0 = 0.f, m1 = 0.f, m2 = 0.f, m3 = 0.f;
#pragma unroll
        for (int t = 0; t < LIF_T; ++t) {
            v4f xt = cur[t];
            m0 = m0 * LIF_BETA + xt.x;
            m1 = m1 * LIF_BETA + xt.y;
            m2 = m2 * LIF_BETA + xt.z;
            m3 = m3 * LIF_BETA + xt.w;

            v4f s;
            s.x = (m0 >= LIF_THRESH) ? 1.f : 0.f;
            s.y = (m1 >= LIF_THRESH) ? 1.f : 0.f;
            s.z = (m2 >= LIF_THRESH) ? 1.f : 0.f;
            s.w = (m3 >= LIF_THRESH) ? 1.f : 0.f;

            m0 = (m0 >= LIF_THRESH) ? 0.f : m0;
            m1 = (m1 >= LIF_THRESH) ? 0.f : m1;
            m2 = (m2 >= LIF_THRESH) ? 0.f : m2;
            m3 = (m3 >= LIF_THRESH) ? 0.f : m3;

            __builtin_nontemporal_store(s, &out[(size_t)t * n4 + c]);
        }

        // Rotate buffers (SSA copies, free after full unroll).
        if (j + 1 < JITER) {
#pragma unroll
            for (int t = 0; t < LIF_T; ++t) cur[t] = nxt[t];
        }
    }
}

extern "C" void kernel_launch(void* const* d_in, const int* in_sizes, int n_in,
                              void* d_out, int out_size, void* d_ws, size_t ws_size,
                              hipStream_t stream) {
    const v4f* x = (const v4f*)d_in[0];
    v4f* out = (v4f*)d_out;

    long long total = in_sizes[0];
    int n = (int)(total / LIF_T);   // 4,194,304 floats per timestep
    int n4 = n / 4;                 // 1,048,576 float4 columns per timestep

    dim3 block(BLOCK);
    dim3 grid(n4 / (BLOCK * JITER));   // 512 blocks -> 2 per CU, 8 waves/CU
    lif_kernel<<<grid, block, 0, stream>>>(x, out, n4);
}